// Round 1
// baseline (318.840 us; speedup 1.0000x reference)
//
#include <hip/hip_runtime.h>
#include <stdint.h>

// Self-attention: x[4,2048,768] fp32, W_q/W_k/W_v [768,768] fp32 -> out[4,2048,768] fp32.
// Pipeline: convert to bf16 -> QKV projection GEMMs (MFMA) -> per-batch S=QK^T (fp32),
// row softmax -> P bf16 -> O = P V. All GEMMs in "A[MxK] @ Bt[NxK]^T" form.

typedef unsigned short u16;
typedef unsigned int u32;

typedef __attribute__((ext_vector_type(4))) float f32x4;
typedef __attribute__((ext_vector_type(8))) __bf16 bf16x8;
typedef __attribute__((ext_vector_type(8))) short s16x8;
typedef __attribute__((ext_vector_type(8))) unsigned short us16x8;

// ---- SFINAE probe: which operand type does the gfx950 bf16 MFMA builtin take? ----
template <class T> T&& declv();

template <typename T, typename V = void>
struct mfma_ok { static constexpr bool value = false; };
template <typename T>
struct mfma_ok<T, decltype((void)__builtin_amdgcn_mfma_f32_16x16x32_bf16(
                     declv<T>(), declv<T>(), declv<f32x4>(), 0, 0, 0))> {
  static constexpr bool value = true;
};

template <bool BF, bool S16> struct pick_frag { typedef us16x8 type; };
template <bool S16> struct pick_frag<true, S16> { typedef bf16x8 type; };
template <> struct pick_frag<false, true> { typedef s16x8 type; };

typedef typename pick_frag<mfma_ok<bf16x8>::value, mfma_ok<s16x8>::value>::type frag_t;

__device__ inline f32x4 mfma16x16x32(frag_t a, frag_t b, f32x4 c) {
  return __builtin_amdgcn_mfma_f32_16x16x32_bf16(a, b, c, 0, 0, 0);
}

// ---- address-space casts for global_load_lds ----
#define AS3(p) ((__attribute__((address_space(3))) void*)(p))
#define AS1c(p) ((__attribute__((address_space(1))) void*)(const void*)(p))

__device__ inline u16 f2bf(float f) {
  union { float f; u32 u; } v; v.f = f;
  u32 r = v.u + 0x7fffu + ((v.u >> 16) & 1u);  // RNE
  return (u16)(r >> 16);
}

__device__ inline void store_val(float* p, float v) { *p = v; }
__device__ inline void store_val(u16* p, float v) { *p = f2bf(v); }

// =====================================================================
// GEMM: C[M x N] = scale * A[M x K] @ Bt[N x K]^T   (A, Bt bf16-as-u16; C fp32 or bf16)
// 128x128 block tile, BK=32, 256 threads (4 waves), each wave 64x64 via 4x4 MFMA tiles.
// LDS layout: k-panels. Panel q (k=q*8..q*8+7): 128 rows x 8 bf16 = 16 B/row,
// A panels at u16 offset q*1024 + m*8; B panels at 4096 + q*1024 + n*8.
// Staged via global_load_lds width=16 (lane-contiguous deposit matches panel layout).
// =====================================================================
template <typename OutT>
__global__ __launch_bounds__(256)
void gemm_bt(const u16* __restrict__ A, const u16* __restrict__ B,
             OutT* __restrict__ C, int K, int lda, int ldb, int ldc,
             long az, long bz, long cz, float scale)
{
  __shared__ alignas(16) u16 smem[8192];  // 16 KB: A 8 KB + B 8 KB

  const int tid  = threadIdx.x;
  const int lane = tid & 63;
  const int wave = tid >> 6;

  A += (long)blockIdx.z * az;
  B += (long)blockIdx.z * bz;
  C += (long)blockIdx.z * cz;

  const int bm0 = blockIdx.x * 128;
  const int bn0 = blockIdx.y * 128;
  const int wm  = (wave & 1) * 64;
  const int wn  = (wave >> 1) * 64;
  const int quad = lane >> 4;
  const int l16  = lane & 15;

  // Wave w stages panel q=w (both 64-row halves) for A and B.
  const u16* gA0 = A + (long)(bm0 + lane) * lda + wave * 8;
  const u16* gA1 = A + (long)(bm0 + 64 + lane) * lda + wave * 8;
  const u16* gB0 = B + (long)(bn0 + lane) * ldb + wave * 8;
  const u16* gB1 = B + (long)(bn0 + 64 + lane) * ldb + wave * 8;
  u16* sA = smem + wave * 1024;         // panel q=wave
  u16* sB = smem + 4096 + wave * 1024;

  f32x4 acc[4][4];
#pragma unroll
  for (int i = 0; i < 4; i++)
#pragma unroll
    for (int j = 0; j < 4; j++) acc[i][j] = f32x4{0.f, 0.f, 0.f, 0.f};

  for (int k0 = 0; k0 < K; k0 += 32) {
    __syncthreads();  // previous iter's ds_reads done before overwrite
    __builtin_amdgcn_global_load_lds(AS1c(gA0 + k0), AS3(sA), 16, 0, 0);
    __builtin_amdgcn_global_load_lds(AS1c(gA1 + k0), AS3(sA + 512), 16, 0, 0);
    __builtin_amdgcn_global_load_lds(AS1c(gB0 + k0), AS3(sB), 16, 0, 0);
    __builtin_amdgcn_global_load_lds(AS1c(gB1 + k0), AS3(sB + 512), 16, 0, 0);
    __syncthreads();  // drains vmcnt before barrier

    frag_t af[4], bf_[4];
#pragma unroll
    for (int mt = 0; mt < 4; mt++)
      af[mt] = *(const frag_t*)(smem + quad * 1024 + (wm + mt * 16 + l16) * 8);
#pragma unroll
    for (int nt = 0; nt < 4; nt++)
      bf_[nt] = *(const frag_t*)(smem + 4096 + quad * 1024 + (wn + nt * 16 + l16) * 8);
#pragma unroll
    for (int mt = 0; mt < 4; mt++)
#pragma unroll
      for (int nt = 0; nt < 4; nt++)
        acc[mt][nt] = mfma16x16x32(af[mt], bf_[nt], acc[mt][nt]);
  }

  // Epilogue. C/D layout: col = lane&15, row = quad*4 + i (m89-verified).
#pragma unroll
  for (int mt = 0; mt < 4; mt++) {
#pragma unroll
    for (int nt = 0; nt < 4; nt++) {
      const int r0 = bm0 + wm + mt * 16 + quad * 4;
      const int c  = bn0 + wn + nt * 16 + l16;
#pragma unroll
      for (int i = 0; i < 4; i++)
        store_val(C + (long)(r0 + i) * ldc + c, acc[mt][nt][i] * scale);
    }
  }
}

// =====================================================================
// fp32 -> bf16 bulk convert (4 elems/thread)
// =====================================================================
__global__ __launch_bounds__(256)
void convert_bf16(const float* __restrict__ in, u16* __restrict__ out, int n4)
{
  int i = blockIdx.x * 256 + threadIdx.x;
  if (i >= n4) return;
  float4 v = reinterpret_cast<const float4*>(in)[i];
  u32 a = (u32)f2bf(v.x) | ((u32)f2bf(v.y) << 16);
  u32 b = (u32)f2bf(v.z) | ((u32)f2bf(v.w) << 16);
  reinterpret_cast<uint2*>(out)[i] = make_uint2(a, b);
}

// =====================================================================
// W [768x768] fp32 -> W^T bf16, LDS-tiled. z selects W_q/W_k/W_v.
// =====================================================================
__global__ __launch_bounds__(256)
void transpose_w(const float* __restrict__ W0, const float* __restrict__ W1,
                 const float* __restrict__ W2, u16* __restrict__ out)
{
  const float* W = blockIdx.z == 0 ? W0 : (blockIdx.z == 1 ? W1 : W2);
  u16* o = out + (size_t)blockIdx.z * 589824;
  __shared__ u16 tile[32][33];
  const int bx = blockIdx.x * 32;  // input col (u)
  const int by = blockIdx.y * 32;  // input row (d)
  const int tx = threadIdx.x, ty = threadIdx.y;
#pragma unroll
  for (int i = 0; i < 32; i += 8)
    tile[ty + i][tx] = f2bf(W[(size_t)(by + ty + i) * 768 + bx + tx]);
  __syncthreads();
#pragma unroll
  for (int i = 0; i < 32; i += 8)
    o[(size_t)(bx + ty + i) * 768 + by + tx] = tile[tx][ty + i];
}

// =====================================================================
// Row softmax over 2048 fp32 -> bf16. One block (256 thr) per row, 8 elems/thread.
// =====================================================================
__global__ __launch_bounds__(256)
void softmax_rows(const float* __restrict__ S, u16* __restrict__ P)
{
  const long row = blockIdx.x;
  const float* s = S + row * 2048;
  u16* p = P + row * 2048;
  const int tid = threadIdx.x;
  const int lane = tid & 63, wave = tid >> 6;

  float4 v0 = reinterpret_cast<const float4*>(s)[2 * tid];
  float4 v1 = reinterpret_cast<const float4*>(s)[2 * tid + 1];
  float vals[8] = {v0.x, v0.y, v0.z, v0.w, v1.x, v1.y, v1.z, v1.w};

  float m = vals[0];
#pragma unroll
  for (int i = 1; i < 8; i++) m = fmaxf(m, vals[i]);
#pragma unroll
  for (int off = 32; off > 0; off >>= 1) m = fmaxf(m, __shfl_xor(m, off, 64));
  __shared__ float red[8];
  if (lane == 0) red[wave] = m;
  __syncthreads();
  m = fmaxf(fmaxf(red[0], red[1]), fmaxf(red[2], red[3]));

  float e[8];
  float sum = 0.f;
#pragma unroll
  for (int i = 0; i < 8; i++) { e[i] = __expf(vals[i] - m); sum += e[i]; }
#pragma unroll
  for (int off = 32; off > 0; off >>= 1) sum += __shfl_xor(sum, off, 64);
  if (lane == 0) red[4 + wave] = sum;
  __syncthreads();
  sum = (red[4] + red[5]) + (red[6] + red[7]);
  float inv = 1.0f / sum;

  u32 w[4];
#pragma unroll
  for (int i = 0; i < 4; i++)
    w[i] = (u32)f2bf(e[2 * i] * inv) | ((u32)f2bf(e[2 * i + 1] * inv) << 16);
  reinterpret_cast<uint4*>(p + tid * 8)[0] = make_uint4(w[0], w[1], w[2], w[3]);
}

// =====================================================================
extern "C" void kernel_launch(void* const* d_in, const int* in_sizes, int n_in,
                              void* d_out, int out_size, void* d_ws, size_t ws_size,
                              hipStream_t stream) {
  (void)in_sizes; (void)n_in; (void)out_size;
  const float* x  = (const float*)d_in[0];
  const float* Wq = (const float*)d_in[1];
  const float* Wk = (const float*)d_in[2];
  const float* Wv = (const float*)d_in[3];
  float* out = (float*)d_out;

  const long SU = 2048L * 768;   // per-batch q/k/v elems
  const long SS = 2048L * 2048;  // per-batch score elems
  const long XN = 8192L * 768;   // all-batch x elems
  const long WN = 768L * 768;

  u16* ws  = (u16*)d_ws;
  u16* xb  = ws;             // x bf16                 [8192 x 768]
  u16* wt  = xb + XN;        // Wq^T,Wk^T,Wv^T bf16    [3][768 x 768]
  u16* Qb  = wt + 3 * WN;    // Q bf16 (pre-scaled)    [8192 x 768]
  u16* Kb  = Qb + XN;        // K bf16                 [8192 x 768]
  u16* Vt  = Kb + XN;        // V^T bf16               [768 x 8192]
  char* rest = (char*)(Vt + XN);
  size_t fixed = (size_t)((char*)rest - (char*)d_ws);
  size_t per_b = (size_t)SS * 4 + (size_t)SS * 2;  // S fp32 + P bf16 per batch

  int g = 1;
  if (ws_size >= fixed + 4 * per_b) g = 4;
  else if (ws_size >= fixed + 2 * per_b) g = 2;

  float* Sb = (float*)rest;
  u16*   Pb = (u16*)(rest + (size_t)g * SS * 4);

  const float qscale = 0.03608439182435161f;  // 1/sqrt(768)

  convert_bf16<<<dim3(6144), dim3(256), 0, stream>>>(x, xb, (int)(XN / 4));
  transpose_w<<<dim3(24, 24, 3), dim3(32, 8), 0, stream>>>(Wq, Wk, Wv, wt);

  // Q = x Wq (scaled), K = x Wk: M=8192, N=768, K=768
  gemm_bt<u16><<<dim3(64, 6, 1), dim3(256), 0, stream>>>(xb, wt, Qb, 768, 768, 768, 768, 0, 0, 0, qscale);
  gemm_bt<u16><<<dim3(64, 6, 1), dim3(256), 0, stream>>>(xb, wt + WN, Kb, 768, 768, 768, 768, 0, 0, 0, 1.0f);
  // V^T = Wv^T x^T: M=768, N=8192 -> Vt[768][8192]
  gemm_bt<u16><<<dim3(6, 64, 1), dim3(256), 0, stream>>>(wt + 2 * WN, xb, Vt, 768, 768, 768, 8192, 0, 0, 0, 1.0f);

  for (int b0 = 0; b0 < 4; b0 += g) {
    int gb = 4 - b0 < g ? 4 - b0 : g;
    // S = Q_b @ K_b^T : M=N=2048, K=768 (scale folded into Q)
    gemm_bt<float><<<dim3(16, 16, gb), dim3(256), 0, stream>>>(
        Qb + b0 * SU, Kb + b0 * SU, Sb, 768, 768, 768, 2048, SU, SU, SS, 1.0f);
    softmax_rows<<<dim3(2048 * gb), dim3(256), 0, stream>>>(Sb, Pb);
    // O_b = P_b @ V_b : M=2048, N=768, K=2048; Bt[n][k] = Vt[u][b*2048+k]
    gemm_bt<float><<<dim3(16, 6, gb), dim3(256), 0, stream>>>(
        Pb, Vt + b0 * 2048, out + b0 * SU, 2048, 2048, 8192, 768, SS, 2048L, SU, 1.0f);
  }
}

// Round 3
// 314.175 us; speedup vs baseline: 1.0148x; 1.0148x over previous
//
#include <hip/hip_runtime.h>
#include <stdint.h>

// Self-attention: x[4,2048,768] fp32, W_q/W_k/W_v [768,768] fp32 -> out[4,2048,768] fp32.
// Pipeline: x->bf16; W->W^T bf16; QK = x @ [Wq^T;Wk^T]^T in ONE gemm (ldc=1536);
// V^T = Wv^T x^T; per batch-group: S = Q K^T (scale in epilogue), row softmax -> P bf16,
// O = P V via split-K=2 partials (reusing Sb) + reduce. No atomics, no memsets.

typedef unsigned short u16;
typedef unsigned int u32;

typedef __attribute__((ext_vector_type(4))) float f32x4;
typedef __attribute__((ext_vector_type(8))) __bf16 bf16x8;
typedef __attribute__((ext_vector_type(8))) short s16x8;
typedef __attribute__((ext_vector_type(8))) unsigned short us16x8;

// ---- SFINAE probe: which operand type does the gfx950 bf16 MFMA builtin take? ----
template <class T> T&& declv();

template <typename T, typename V = void>
struct mfma_ok { static constexpr bool value = false; };
template <typename T>
struct mfma_ok<T, decltype((void)__builtin_amdgcn_mfma_f32_16x16x32_bf16(
                     declv<T>(), declv<T>(), declv<f32x4>(), 0, 0, 0))> {
  static constexpr bool value = true;
};

template <bool BF, bool S16> struct pick_frag { typedef us16x8 type; };
template <bool S16> struct pick_frag<true, S16> { typedef bf16x8 type; };
template <> struct pick_frag<false, true> { typedef s16x8 type; };

typedef typename pick_frag<mfma_ok<bf16x8>::value, mfma_ok<s16x8>::value>::type frag_t;

__device__ inline f32x4 mfma16x16x32(frag_t a, frag_t b, f32x4 c) {
  return __builtin_amdgcn_mfma_f32_16x16x32_bf16(a, b, c, 0, 0, 0);
}

// ---- address-space casts for global_load_lds ----
#define AS3(p) ((__attribute__((address_space(3))) void*)(p))
#define AS1c(p) ((__attribute__((address_space(1))) void*)(const void*)(p))

__device__ inline u16 f2bf(float f) {
  union { float f; u32 u; } v; v.f = f;
  u32 r = v.u + 0x7fffu + ((v.u >> 16) & 1u);  // RNE
  return (u16)(r >> 16);
}

__device__ inline void store_val(float* p, float v) { *p = v; }
__device__ inline void store_val(u16* p, float v) { *p = f2bf(v); }

// =====================================================================
// GEMM: C[M x N] = scale * A[M x K] @ Bt[N x K]^T   (A, Bt bf16-as-u16; C fp32 or bf16)
// 128x128 block tile, BK=32, 256 threads (4 waves), each wave 64x64 via 4x4 MFMA tiles.
// LDS k-panel layout staged via global_load_lds width=16.
// All global base addresses / lda / ldb must be 16B-aligned (8-element) multiples.
// =====================================================================
template <typename OutT>
__global__ __launch_bounds__(256)
void gemm_bt(const u16* __restrict__ A, const u16* __restrict__ B,
             OutT* __restrict__ C, int K, int lda, int ldb, int ldc,
             long az, long bz, long cz, float scale)
{
  __shared__ alignas(16) u16 smem[8192];  // 16 KB: A 8 KB + B 8 KB

  const int tid  = threadIdx.x;
  const int lane = tid & 63;
  const int wave = tid >> 6;
  const int quad = lane >> 4;
  const int l16  = lane & 15;

  A += (long)blockIdx.z * az;
  B += (long)blockIdx.z * bz;
  C += (long)blockIdx.z * cz;

  const int bm0 = blockIdx.x * 128;
  const int bn0 = blockIdx.y * 128;
  const int wm  = (wave & 1) * 64;
  const int wn  = (wave >> 1) * 64;

  // Wave w stages panel q=w (both 64-row halves) for A and B.
  const u16* gA0 = A + (long)(bm0 + lane) * lda + wave * 8;
  const u16* gA1 = A + (long)(bm0 + 64 + lane) * lda + wave * 8;
  const u16* gB0 = B + (long)(bn0 + lane) * ldb + wave * 8;
  const u16* gB1 = B + (long)(bn0 + 64 + lane) * ldb + wave * 8;
  u16* sA = smem + wave * 1024;         // panel q=wave
  u16* sB = smem + 4096 + wave * 1024;

  f32x4 acc[4][4];
#pragma unroll
  for (int i = 0; i < 4; i++)
#pragma unroll
    for (int j = 0; j < 4; j++) acc[i][j] = f32x4{0.f, 0.f, 0.f, 0.f};

  for (int k0 = 0; k0 < K; k0 += 32) {
    __syncthreads();  // previous iter's ds_reads done before overwrite
    __builtin_amdgcn_global_load_lds(AS1c(gA0 + k0), AS3(sA), 16, 0, 0);
    __builtin_amdgcn_global_load_lds(AS1c(gA1 + k0), AS3(sA + 512), 16, 0, 0);
    __builtin_amdgcn_global_load_lds(AS1c(gB0 + k0), AS3(sB), 16, 0, 0);
    __builtin_amdgcn_global_load_lds(AS1c(gB1 + k0), AS3(sB + 512), 16, 0, 0);
    __syncthreads();  // drains vmcnt before barrier

    frag_t af[4], bf_[4];
#pragma unroll
    for (int mt = 0; mt < 4; mt++)
      af[mt] = *(const frag_t*)(smem + quad * 1024 + (wm + mt * 16 + l16) * 8);
#pragma unroll
    for (int nt = 0; nt < 4; nt++)
      bf_[nt] = *(const frag_t*)(smem + 4096 + quad * 1024 + (wn + nt * 16 + l16) * 8);
#pragma unroll
    for (int mt = 0; mt < 4; mt++)
#pragma unroll
      for (int nt = 0; nt < 4; nt++)
        acc[mt][nt] = mfma16x16x32(af[mt], bf_[nt], acc[mt][nt]);
  }

  // Epilogue. C/D layout: col = lane&15, row = quad*4 + i (m89-verified).
#pragma unroll
  for (int mt = 0; mt < 4; mt++) {
#pragma unroll
    for (int nt = 0; nt < 4; nt++) {
      const int r0 = bm0 + wm + mt * 16 + quad * 4;
      const int c  = bn0 + wn + nt * 16 + l16;
#pragma unroll
      for (int i = 0; i < 4; i++)
        store_val(C + (long)(r0 + i) * ldc + c, acc[mt][nt][i] * scale);
    }
  }
}

// =====================================================================
// PV split-K=2 partials: grid (16, 6, gb*2); z = batch*2 + chunk.
// A = P[batch] (lda 2048), chunk k-offset 1024; B = Vt cols (ldb 8192).
// C = partials: Pw + batch*(2*SU) + chunk*SU, ldc=768.
// =====================================================================
__global__ __launch_bounds__(256)
void gemm_pv_part(const u16* __restrict__ P, const u16* __restrict__ Vt,
                  float* __restrict__ Pw)
{
  const long SU = 2048L * 768;
  const int batch = blockIdx.z >> 1;
  const int chunk = blockIdx.z & 1;
  const u16* A = P + (long)batch * (2048L * 2048) + chunk * 1024;
  const u16* B = Vt + (long)batch * 2048 + chunk * 1024;
  float* C = Pw + (long)batch * (2 * SU) + (long)chunk * SU;

  // inline the gemm core via a direct call pattern (duplicate of gemm_bt body)
  __shared__ alignas(16) u16 smem[8192];
  const int tid  = threadIdx.x;
  const int lane = tid & 63;
  const int wave = tid >> 6;
  const int quad = lane >> 4;
  const int l16  = lane & 15;
  const int bm0 = blockIdx.x * 128;
  const int bn0 = blockIdx.y * 128;
  const int wm  = (wave & 1) * 64;
  const int wn  = (wave >> 1) * 64;
  const int lda = 2048, ldb = 8192, ldc = 768, K = 1024;

  const u16* gA0 = A + (long)(bm0 + lane) * lda + wave * 8;
  const u16* gA1 = A + (long)(bm0 + 64 + lane) * lda + wave * 8;
  const u16* gB0 = B + (long)(bn0 + lane) * ldb + wave * 8;
  const u16* gB1 = B + (long)(bn0 + 64 + lane) * ldb + wave * 8;
  u16* sA = smem + wave * 1024;
  u16* sB = smem + 4096 + wave * 1024;

  f32x4 acc[4][4];
#pragma unroll
  for (int i = 0; i < 4; i++)
#pragma unroll
    for (int j = 0; j < 4; j++) acc[i][j] = f32x4{0.f, 0.f, 0.f, 0.f};

  for (int k0 = 0; k0 < K; k0 += 32) {
    __syncthreads();
    __builtin_amdgcn_global_load_lds(AS1c(gA0 + k0), AS3(sA), 16, 0, 0);
    __builtin_amdgcn_global_load_lds(AS1c(gA1 + k0), AS3(sA + 512), 16, 0, 0);
    __builtin_amdgcn_global_load_lds(AS1c(gB0 + k0), AS3(sB), 16, 0, 0);
    __builtin_amdgcn_global_load_lds(AS1c(gB1 + k0), AS3(sB + 512), 16, 0, 0);
    __syncthreads();

    frag_t af[4], bf_[4];
#pragma unroll
    for (int mt = 0; mt < 4; mt++)
      af[mt] = *(const frag_t*)(smem + quad * 1024 + (wm + mt * 16 + l16) * 8);
#pragma unroll
    for (int nt = 0; nt < 4; nt++)
      bf_[nt] = *(const frag_t*)(smem + 4096 + quad * 1024 + (wn + nt * 16 + l16) * 8);
#pragma unroll
    for (int mt = 0; mt < 4; mt++)
#pragma unroll
      for (int nt = 0; nt < 4; nt++)
        acc[mt][nt] = mfma16x16x32(af[mt], bf_[nt], acc[mt][nt]);
  }

#pragma unroll
  for (int mt = 0; mt < 4; mt++) {
#pragma unroll
    for (int nt = 0; nt < 4; nt++) {
      const int r0 = bm0 + wm + mt * 16 + quad * 4;
      const int c  = bn0 + wn + nt * 16 + l16;
#pragma unroll
      for (int i = 0; i < 4; i++)
        C[(long)(r0 + i) * ldc + c] = acc[mt][nt][i];
    }
  }
}

// =====================================================================
// Reduce two split-K partials into out: out[i] = Pw[b][0][i] + Pw[b][1][i].
// float4 per thread; total gb*SU elems.
// =====================================================================
__global__ __launch_bounds__(256)
void reduce_pv(const float* __restrict__ Pw, float* __restrict__ out, int total4)
{
  int idx = blockIdx.x * 256 + threadIdx.x;
  if (idx >= total4) return;
  const int per_b4 = 393216;  // SU/4
  int b = idx / per_b4;
  int w = idx - b * per_b4;
  const float4* p0 = (const float4*)(Pw + (long)b * 2 * 1572864);
  const float4* p1 = (const float4*)(Pw + (long)b * 2 * 1572864 + 1572864);
  float4 a = p0[w], c = p1[w];
  float4 r; r.x = a.x + c.x; r.y = a.y + c.y; r.z = a.z + c.z; r.w = a.w + c.w;
  ((float4*)out)[idx] = r;
}

// =====================================================================
// fp32 -> bf16 bulk convert (4 elems/thread)
// =====================================================================
__global__ __launch_bounds__(256)
void convert_bf16(const float* __restrict__ in, u16* __restrict__ out, int n4)
{
  int i = blockIdx.x * 256 + threadIdx.x;
  if (i >= n4) return;
  float4 v = reinterpret_cast<const float4*>(in)[i];
  u32 a = (u32)f2bf(v.x) | ((u32)f2bf(v.y) << 16);
  u32 b = (u32)f2bf(v.z) | ((u32)f2bf(v.w) << 16);
  reinterpret_cast<uint2*>(out)[i] = make_uint2(a, b);
}

// =====================================================================
// W [768x768] fp32 -> W^T bf16, LDS-tiled. z selects W_q/W_k/W_v.
// =====================================================================
__global__ __launch_bounds__(256)
void transpose_w(const float* __restrict__ W0, const float* __restrict__ W1,
                 const float* __restrict__ W2, u16* __restrict__ out)
{
  const float* W = blockIdx.z == 0 ? W0 : (blockIdx.z == 1 ? W1 : W2);
  u16* o = out + (size_t)blockIdx.z * 589824;
  __shared__ u16 tile[32][33];
  const int bx = blockIdx.x * 32;  // input col (u)
  const int by = blockIdx.y * 32;  // input row (d)
  const int tx = threadIdx.x, ty = threadIdx.y;
#pragma unroll
  for (int i = 0; i < 32; i += 8)
    tile[ty + i][tx] = f2bf(W[(size_t)(by + ty + i) * 768 + bx + tx]);
  __syncthreads();
#pragma unroll
  for (int i = 0; i < 32; i += 8)
    o[(size_t)(bx + ty + i) * 768 + by + tx] = tile[tx][ty + i];
}

// =====================================================================
// Row softmax over 2048 fp32 -> bf16. One block (256 thr) per row, 8 elems/thread.
// =====================================================================
__global__ __launch_bounds__(256)
void softmax_rows(const float* __restrict__ S, u16* __restrict__ P)
{
  const long row = blockIdx.x;
  const float* s = S + row * 2048;
  u16* p = P + row * 2048;
  const int tid = threadIdx.x;
  const int lane = tid & 63, wave = tid >> 6;

  float4 v0 = reinterpret_cast<const float4*>(s)[2 * tid];
  float4 v1 = reinterpret_cast<const float4*>(s)[2 * tid + 1];
  float vals[8] = {v0.x, v0.y, v0.z, v0.w, v1.x, v1.y, v1.z, v1.w};

  float m = vals[0];
#pragma unroll
  for (int i = 1; i < 8; i++) m = fmaxf(m, vals[i]);
#pragma unroll
  for (int off = 32; off > 0; off >>= 1) m = fmaxf(m, __shfl_xor(m, off, 64));
  __shared__ float red[8];
  if (lane == 0) red[wave] = m;
  __syncthreads();
  m = fmaxf(fmaxf(red[0], red[1]), fmaxf(red[2], red[3]));

  float e[8];
  float sum = 0.f;
#pragma unroll
  for (int i = 0; i < 8; i++) { e[i] = __expf(vals[i] - m); sum += e[i]; }
#pragma unroll
  for (int off = 32; off > 0; off >>= 1) sum += __shfl_xor(sum, off, 64);
  if (lane == 0) red[4 + wave] = sum;
  __syncthreads();
  sum = (red[4] + red[5]) + (red[6] + red[7]);
  float inv = 1.0f / sum;

  u32 w[4];
#pragma unroll
  for (int i = 0; i < 4; i++)
    w[i] = (u32)f2bf(e[2 * i] * inv) | ((u32)f2bf(e[2 * i + 1] * inv) << 16);
  reinterpret_cast<uint4*>(p + tid * 8)[0] = make_uint4(w[0], w[1], w[2], w[3]);
}

// =====================================================================
extern "C" void kernel_launch(void* const* d_in, const int* in_sizes, int n_in,
                              void* d_out, int out_size, void* d_ws, size_t ws_size,
                              hipStream_t stream) {
  (void)in_sizes; (void)n_in; (void)out_size;
  const float* x  = (const float*)d_in[0];
  const float* Wq = (const float*)d_in[1];
  const float* Wk = (const float*)d_in[2];
  const float* Wv = (const float*)d_in[3];
  float* out = (float*)d_out;

  const long SU = 2048L * 768;   // per-batch q/k/v elems
  const long SS = 2048L * 2048;  // per-batch score elems
  const long XN = 8192L * 768;   // all-batch x elems
  const long WN = 768L * 768;
  const long QKN = 8192L * 1536; // QK interleaved elems

  u16* ws  = (u16*)d_ws;
  u16* xb  = ws;             // x bf16                  [8192 x 768]
  u16* wt  = xb + XN;        // Wq^T,Wk^T,Wv^T bf16     [3][768 x 768]
  u16* qk  = wt + 3 * WN;    // QK interleaved bf16     [8192 x 1536] (Q cols 0..767, K cols 768..1535)
  u16* Vt  = qk + QKN;       // V^T bf16                [768 x 8192]
  char* rest = (char*)(Vt + XN);
  size_t fixed = (size_t)((char*)rest - (char*)d_ws);
  size_t per_b = (size_t)SS * 4 + (size_t)SS * 2;  // S fp32 + P bf16 per batch

  int g = 1;
  if (ws_size >= fixed + 4 * per_b) g = 4;
  else if (ws_size >= fixed + 2 * per_b) g = 2;

  float* Sb = (float*)rest;                       // scores; later reused for PV partials
  u16*   Pb = (u16*)(rest + (size_t)g * SS * 4);

  const float qscale = 0.03608439182435161f;  // 1/sqrt(768)

  convert_bf16<<<dim3(6144), dim3(256), 0, stream>>>(x, xb, (int)(XN / 4));
  transpose_w<<<dim3(24, 24, 3), dim3(32, 8), 0, stream>>>(Wq, Wk, Wv, wt);

  // QK = x @ [Wq^T;Wk^T]^T : M=8192, N=1536, K=768 -> 768 blocks
  gemm_bt<u16><<<dim3(64, 12, 1), dim3(256), 0, stream>>>(
      xb, wt, qk, 768, 768, 768, 1536, 0, 0, 0, 1.0f);
  // V^T = Wv^T x^T : M=768, N=8192
  gemm_bt<u16><<<dim3(6, 64, 1), dim3(256), 0, stream>>>(
      wt + 2 * WN, xb, Vt, 768, 768, 768, 8192, 0, 0, 0, 1.0f);

  for (int b0 = 0; b0 < 4; b0 += g) {
    int gb = 4 - b0 < g ? 4 - b0 : g;
    // S = Q_b @ K_b^T : M=N=2048, K=768; scale applied in epilogue.
    // Q rows: qk + (b0*2048)*1536, lda=1536; K rows: same +768 cols, ldb=1536.
    gemm_bt<float><<<dim3(16, 16, gb), dim3(256), 0, stream>>>(
        qk + (long)b0 * 2048 * 1536, qk + (long)b0 * 2048 * 1536 + 768, Sb,
        768, 1536, 1536, 2048, 2048L * 1536, 2048L * 1536, SS, qscale);
    softmax_rows<<<dim3(2048 * gb), dim3(256), 0, stream>>>(Sb, Pb);
    // O partials: P_b @ V_b split-K=2 into Sb region (dead after softmax)
    gemm_pv_part<<<dim3(16, 6, gb * 2), dim3(256), 0, stream>>>(
        Pb, Vt + (long)b0 * 2048, (float*)Sb);
    reduce_pv<<<dim3(gb * 1536), dim3(256), 0, stream>>>(
        (float*)Sb, out + (long)b0 * SU, gb * 393216);
  }
}